// Round 1
// 272.967 us; speedup vs baseline: 1.0519x; 1.0519x over previous
//
#include <hip/hip_runtime.h>
#include <cstdint>

// B=4, L=2048, H=512, HEADS=8, D=64.
// Only the DIAGONAL of softmax(scores) is consumed:
//   diag_i = exp(s_ii) / sum_j exp(s_ij),
//   s_ij = q_i.k_j + q_i.Wp[1983+j-i...] + Wp_b[l-1+j-i]
// Logits in log2 units (q pre-scaled by log2e/8 via prep-scaled Wq, bias by log2e).

typedef unsigned short u16;
typedef __bf16 bf16x8 __attribute__((ext_vector_type(8)));
typedef __bf16 bf16x2 __attribute__((ext_vector_type(2)));
typedef float  f32x16 __attribute__((ext_vector_type(16)));
typedef uint32_t __attribute__((address_space(1))) as1_u32;
typedef uint32_t __attribute__((address_space(3))) as3_u32;

__device__ __forceinline__ u16 f2bf(float f) {
  __bf16 h = (__bf16)f;                    // v_cvt_pk_bf16_f32 (RNE) on gfx950
  return __builtin_bit_cast(u16, h);
}
__device__ __forceinline__ uint32_t pkbf(float a, float b) {
  bf16x2 v; v[0] = (__bf16)a; v[1] = (__bf16)b;
  return __builtin_bit_cast(uint32_t, v);
}
__device__ __forceinline__ float bf2f(u16 u) {
  return __uint_as_float(((uint32_t)u) << 16);
}
__device__ __forceinline__ void gl_lds16(const void* g, void* l) {
  __builtin_amdgcn_global_load_lds((const as1_u32*)g, (as3_u32*)l, 16, 0, 0);
}

// ---------------------------------------------------------------------------
// Prep: fp32 -> bf16 for q_in/k_in/v_in, Wq/Wk/Wv/Wo, Wp (padded to 4096 rows)
// Wq is pre-scaled by log2e/8 so the QKV epilogue needs no multiply.
// ---------------------------------------------------------------------------
__global__ __launch_bounds__(256) void prep_kernel(
    const float* __restrict__ qin, const float* __restrict__ kin, const float* __restrict__ vin,
    const float* __restrict__ wq,  const float* __restrict__ wk,  const float* __restrict__ wv,
    const float* __restrict__ wo,  const float* __restrict__ wp,
    u16* __restrict__ xq, u16* __restrict__ xk, u16* __restrict__ xv,
    u16* __restrict__ bwq, u16* __restrict__ bwk, u16* __restrict__ bwv,
    u16* __restrict__ bwo, u16* __restrict__ bwp) {
  long u = (long)blockIdx.x * 256 + threadIdx.x;
  const float* src; u16* dst; long off; float qs = 1.0f;
  if      (u < 524288L)  { src = qin; dst = xq;  off = u; }
  else if (u < 1048576L) { src = kin; dst = xk;  off = u - 524288L; }
  else if (u < 1572864L) { src = vin; dst = xv;  off = u - 1048576L; }
  else if (u < 1605632L) { src = wq;  dst = bwq; off = u - 1572864L; qs = 0.18033688f; }
  else if (u < 1638400L) { src = wk;  dst = bwk; off = u - 1605632L; }
  else if (u < 1671168L) { src = wv;  dst = bwv; off = u - 1638400L; }
  else if (u < 1703936L) { src = wo;  dst = bwo; off = u - 1671168L; }
  else if (u < 1736696L) { src = wp;  dst = bwp; off = u - 1703936L; }
  else {  // zero-fill Wp pad row 4095
    long o = (u - 1736696L) * 8 + 262080L;
    uint4 z = {0u, 0u, 0u, 0u};
    *(uint4*)(bwp + o) = z;
    return;
  }
  const float4* s4 = (const float4*)(src + off * 8);
  float4 a = s4[0], b = s4[1];
  uint32_t p0 = pkbf(a.x * qs, a.y * qs);
  uint32_t p1 = pkbf(a.z * qs, a.w * qs);
  uint32_t p2 = pkbf(b.x * qs, b.y * qs);
  uint32_t p3 = pkbf(b.z * qs, b.w * qs);
  uint4 o = {p0, p1, p2, p3};
  *(uint4*)(dst + off * 8) = o;
}

// ---------------------------------------------------------------------------
// gemm_bt: C = A @ W^T + bias (fp32 out, row-major). A: 8192x512 bf16.
// 128x128 tile, 4 waves, 32x32x16 MFMA, BK=32, global_load_lds staging.
// Bias folded into the MFMA accumulator init (C-col = lane&31, uniform per reg).
// ---------------------------------------------------------------------------
__global__ __launch_bounds__(256) void gemm_bt(
    const u16* __restrict__ A, const u16* __restrict__ W, const float* __restrict__ bias,
    float* __restrict__ ofp) {
  __shared__ u16 Al[128 * 32];
  __shared__ u16 Bl[128 * 32];
  const int tid = threadIdx.x;
  const int lane = tid & 63, w = tid >> 6;
  const int wi = w >> 1, wj = w & 1;
  const int m0 = (blockIdx.x >> 2) * 128, n0 = (blockIdx.x & 3) * 128;
  const int l31 = lane & 31;

  float bv0 = bias[n0 + 64 * wj + l31];
  float bv1 = bias[n0 + 64 * wj + 32 + l31];
  f32x16 acc[2][2];
#pragma unroll
  for (int i = 0; i < 2; ++i)
#pragma unroll
    for (int r = 0; r < 16; ++r) { acc[i][0][r] = bv0; acc[i][1][r] = bv1; }

  for (int kb = 0; kb < 16; ++kb) {
#pragma unroll
    for (int c = 0; c < 2; ++c) {
      int s = c * 256 + w * 64 + lane;
      int r = s >> 2, ch = s & 3;
      int gch = ch ^ ((r >> 1) & 3);
      gl_lds16(A + (long)(m0 + r) * 512 + kb * 32 + gch * 8, (char*)Al + (c * 256 + w * 64) * 16);
      gl_lds16(W + (long)(n0 + r) * 512 + kb * 32 + gch * 8, (char*)Bl + (c * 256 + w * 64) * 16);
    }
    __syncthreads();
    bf16x8 af[2][2], bfr[2][2];
#pragma unroll
    for (int mt = 0; mt < 2; ++mt)
#pragma unroll
      for (int ks = 0; ks < 2; ++ks) {
        int r = 64 * wi + 32 * mt + l31;
        int ch = 2 * ks + (lane >> 5);
        af[mt][ks] = *(const bf16x8*)((char*)Al + (r * 4 + (ch ^ ((r >> 1) & 3))) * 16);
      }
#pragma unroll
    for (int nt = 0; nt < 2; ++nt)
#pragma unroll
      for (int ks = 0; ks < 2; ++ks) {
        int r = 64 * wj + 32 * nt + l31;
        int ch = 2 * ks + (lane >> 5);
        bfr[nt][ks] = *(const bf16x8*)((char*)Bl + (r * 4 + (ch ^ ((r >> 1) & 3))) * 16);
      }
#pragma unroll
    for (int mt = 0; mt < 2; ++mt)
#pragma unroll
      for (int nt = 0; nt < 2; ++nt)
#pragma unroll
        for (int ks = 0; ks < 2; ++ks)
          acc[mt][nt] = __builtin_amdgcn_mfma_f32_32x32x16_bf16(af[mt][ks], bfr[nt][ks],
                                                                acc[mt][nt], 0, 0, 0);
    __syncthreads();
  }
#pragma unroll
  for (int nt = 0; nt < 2; ++nt) {
    int n = n0 + 64 * wj + 32 * nt + l31;
#pragma unroll
    for (int mt = 0; mt < 2; ++mt) {
#pragma unroll
      for (int r = 0; r < 16; ++r) {
        int row = m0 + 64 * wi + 32 * mt + (r & 3) + 8 * (r >> 2) + 4 * (lane >> 5);
        ofp[(long)row * 512 + n] = acc[mt][nt][r];
      }
    }
  }
}

// ---------------------------------------------------------------------------
// Fused Q/K/V projection: 768 blocks (3 matrices x 256 tiles).
// Bias folded into accumulator init; Wq was pre-scaled in prep so no epilogue mul.
// ---------------------------------------------------------------------------
__global__ __launch_bounds__(256) void qkv_gemm(
    const u16* __restrict__ xq, const u16* __restrict__ xk, const u16* __restrict__ xv,
    const u16* __restrict__ wqp, const u16* __restrict__ wkp, const u16* __restrict__ wvp,
    const float* __restrict__ bq, const float* __restrict__ bk, const float* __restrict__ bv,
    u16* __restrict__ oq, u16* __restrict__ ok, u16* __restrict__ ov) {
  __shared__ u16 Al[128 * 32];
  __shared__ u16 Bl[128 * 32];
  const int mat = blockIdx.x >> 8;
  const int tile = blockIdx.x & 255;
  const u16* A = (mat == 0) ? xq : (mat == 1) ? xk : xv;
  const u16* W = (mat == 0) ? wqp : (mat == 1) ? wkp : wvp;
  const float* bias = (mat == 0) ? bq : (mat == 1) ? bk : bv;
  u16* obf = (mat == 0) ? oq : (mat == 1) ? ok : ov;
  const float bsc = (mat == 0) ? 0.18033688f : 1.0f;  // bias gets the log2e/8 too

  const int tid = threadIdx.x;
  const int lane = tid & 63, w = tid >> 6;
  const int wi = w >> 1, wj = w & 1;
  const int m0 = (tile >> 2) * 128, n0 = (tile & 3) * 128;
  const int l31 = lane & 31;

  float bv0 = bias[n0 + 64 * wj + l31] * bsc;
  float bv1 = bias[n0 + 64 * wj + 32 + l31] * bsc;
  f32x16 acc[2][2];
#pragma unroll
  for (int i = 0; i < 2; ++i)
#pragma unroll
    for (int r = 0; r < 16; ++r) { acc[i][0][r] = bv0; acc[i][1][r] = bv1; }

  for (int kb = 0; kb < 16; ++kb) {
#pragma unroll
    for (int c = 0; c < 2; ++c) {
      int s = c * 256 + w * 64 + lane;
      int r = s >> 2, ch = s & 3;
      int gch = ch ^ ((r >> 1) & 3);
      gl_lds16(A + (long)(m0 + r) * 512 + kb * 32 + gch * 8, (char*)Al + (c * 256 + w * 64) * 16);
      gl_lds16(W + (long)(n0 + r) * 512 + kb * 32 + gch * 8, (char*)Bl + (c * 256 + w * 64) * 16);
    }
    __syncthreads();
    bf16x8 af[2][2], bfr[2][2];
#pragma unroll
    for (int mt = 0; mt < 2; ++mt)
#pragma unroll
      for (int ks = 0; ks < 2; ++ks) {
        int r = 64 * wi + 32 * mt + l31;
        int ch = 2 * ks + (lane >> 5);
        af[mt][ks] = *(const bf16x8*)((char*)Al + (r * 4 + (ch ^ ((r >> 1) & 3))) * 16);
      }
#pragma unroll
    for (int nt = 0; nt < 2; ++nt)
#pragma unroll
      for (int ks = 0; ks < 2; ++ks) {
        int r = 64 * wj + 32 * nt + l31;
        int ch = 2 * ks + (lane >> 5);
        bfr[nt][ks] = *(const bf16x8*)((char*)Bl + (r * 4 + (ch ^ ((r >> 1) & 3))) * 16);
      }
#pragma unroll
    for (int mt = 0; mt < 2; ++mt)
#pragma unroll
      for (int nt = 0; nt < 2; ++nt)
#pragma unroll
        for (int ks = 0; ks < 2; ++ks)
          acc[mt][nt] = __builtin_amdgcn_mfma_f32_32x32x16_bf16(af[mt][ks], bfr[nt][ks],
                                                                acc[mt][nt], 0, 0, 0);
    __syncthreads();
  }
#pragma unroll
  for (int nt = 0; nt < 2; ++nt) {
    int n = n0 + 64 * wj + 32 * nt + l31;
#pragma unroll
    for (int mt = 0; mt < 2; ++mt) {
#pragma unroll
      for (int r = 0; r < 16; ++r) {
        int row = m0 + 64 * wi + 32 * mt + (r & 3) + 8 * (r >> 2) + 4 * (lane >> 5);
        int b = row >> 11, l = row & 2047, h = n >> 6, d = n & 63;
        obf[(((long)(b * 8 + h)) * 2048 + l) * 64 + d] = f2bf(acc[mt][nt][r]);
      }
    }
  }
}

// ---------------------------------------------------------------------------
// Attention. One block per (b,h, 64-row i-tile); 4 waves; 4 blocks/CU.
// Changes vs previous version:
//  - XCD swizzle: all 32 i-tiles of one (b,h) map to one XCD (K panel L2-fits).
//  - Mirror ring: rows 256..282 duplicate rows 0..26 so all 16 combine reads
//    are ds_read_u16 at compile-time immediate offsets from ONE base (no per-r
//    address math, no &255 per element). Bank pattern unchanged (conflict-free).
//  - P is the MFMA C-init for the score tile (reads moved before the MFMA),
//    eliminating the 16 accS+p adds. K-frags load to VGPRs pre-barrier.
//  - Wp bias bv is the C-init of the pos MFMA (uniform across regs per lane).
//  - bf16 packing via v_cvt_pk_bf16_f32 (casts), not manual RTNE.
//  - Diagonal capture under a wave-uniform branch (1 of 32 iterations).
// Ring slot safety with ONE barrier/iter: iter jt writes slot (jt+2)&3; reads
// in the same unbarriered window (iters jt,jt+1... wait: iter jt post-barrier
// reads touch slots jt&3,(jt+1)&3 only) never touch (jt+2)&3. Mirror rows are
// written together with their slot-0 source rows.
// ---------------------------------------------------------------------------
__global__ __launch_bounds__(256, 4) void attn_kernel(
    const u16* __restrict__ qw, const u16* __restrict__ kw, const u16* __restrict__ vw,
    const u16* __restrict__ wpw, const float* __restrict__ wpb, u16* __restrict__ outp) {
  __shared__ u16 Pl[283 * 66];     // 256-row ring + 27 mirror rows, stride 66
  __shared__ float sdiag[64];
  __shared__ float rssum[128];
  __shared__ float attw[64];

  const int tid = threadIdx.x, lane = tid & 63, w = tid >> 6;
  const int wi = w >> 1, wj = w & 1;
  // XCD swizzle: dispatch round-robins blockIdx%8 across XCDs; give XCD x the
  // 32 i-tiles of bh ≡ x (mod 8) so each XCD's L2 holds only 4 K/Q panels.
  const int sbi = blockIdx.x;
  const int kk_ = sbi >> 3;
  const int bh = (sbi & 7) + 8 * (kk_ >> 5);
  const int it = kk_ & 31;
  const int i0 = it * 64, base = 1984 - i0;
  const u16* qb = qw + (long)bh * 2048 * 64;
  const u16* kb = kw + (long)bh * 2048 * 64;
  const u16* vb = vw + (long)bh * 2048 * 64;

  const int l31 = lane & 31, lh = lane >> 5;
  const int iibase = 32 * wi + 4 * lh;

  // A-fragments: Q rows i0+32wi+(lane&31), full K=64 (log2e/8 pre-scaled)
  bf16x8 aq[4];
  {
    int row = i0 + 32 * wi + l31;
    const u16* p = qb + (long)row * 64 + lh * 8;
#pragma unroll
    for (int kk = 0; kk < 4; ++kk) aq[kk] = *(const bf16x8*)(p + kk * 16);
  }

  float rsum[16];
#pragma unroll
  for (int r = 0; r < 16; ++r) rsum[r] = 0.f;

  // compute P block g (64 cols of the rolling window) and write to ring
  auto pblock = [&](int g) {
    int brow = base + 64 * g + 32 * wj + l31;   // Wp row for this lane's col
    const u16* bp = wpw + (long)brow * 64 + lh * 8;
    int bidx = brow > 4094 ? 4094 : brow;       // clamp (clamped cell never read)
    float bv = wpb[bidx] * 1.44269504f;         // log2e
    f32x16 accP;
#pragma unroll
    for (int r = 0; r < 16; ++r) accP[r] = bv;  // bias as C-init
#pragma unroll
    for (int kk = 0; kk < 4; ++kk) {
      bf16x8 bw = *(const bf16x8*)(bp + kk * 16);
      accP = __builtin_amdgcn_mfma_f32_32x32x16_bf16(aq[kk], bw, accP, 0, 0, 0);
    }
    int colp = (g & 3) * 64 + 32 * wj + l31;    // phys ring row
    uint32_t pk0[8];
#pragma unroll
    for (int m = 0; m < 4; ++m) {
      pk0[2 * m]     = pkbf(accP[4 * m + 0], accP[4 * m + 1]);
      pk0[2 * m + 1] = pkbf(accP[4 * m + 2], accP[4 * m + 3]);
    }
    u16* wl = &Pl[colp * 66 + iibase];
#pragma unroll
    for (int m = 0; m < 4; ++m) {
      *(uint32_t*)(wl + 8 * m) = pk0[2 * m];
      *(uint32_t*)(wl + 8 * m + 2) = pk0[2 * m + 1];
    }
    if (((g & 3) == 0) && (wj == 0)) {          // mirror rows 0..26 -> 256..282
      if (l31 < 27) {
        u16* wl2 = wl + 256 * 66;
#pragma unroll
        for (int m = 0; m < 4; ++m) {
          *(uint32_t*)(wl2 + 8 * m) = pk0[2 * m];
          *(uint32_t*)(wl2 + 8 * m + 2) = pk0[2 * m + 1];
        }
      }
    }
  };

  pblock(0);
  pblock(1);

  const int W1c = 63 + 32 * wj + l31 - iibase;

  for (int jt = 0; jt < 32; ++jt) {
    // K-fragments for this tile: global -> VGPR, no barrier dependency
    bf16x8 kf[4];
    {
      const u16* bp = kb + (long)(jt * 64 + 32 * wj + l31) * 64 + lh * 8;
#pragma unroll
      for (int kk = 0; kk < 4; ++kk) kf[kk] = *(const bf16x8*)(bp + kk * 16);
    }
    if (jt <= 30) pblock(jt + 2);   // window block for NEXT-next read
    __syncthreads();                // the ONLY barrier per iteration

    // P reads: one base, 16 immediate-offset ds_read_u16 via the mirror rows
    f32x16 accS;
    {
      int W1 = 64 * jt + W1c;
      int b_ = ((W1 - 27) & 255) + 27;            // unwrapped row in [27,282]
      const u16* rb = &Pl[b_ * 66 + iibase - 27 * 65];
#pragma unroll
      for (int r = 0; r < 16; ++r) {
        const int lrr = (r & 3) + 8 * (r >> 2);
        accS[r] = bf2f(rb[(27 - lrr) * 65]);      // offset imm = (27-lrr)*130 B
      }
    }
#pragma unroll
    for (int kk = 0; kk < 4; ++kk)
      accS = __builtin_amdgcn_mfma_f32_32x32x16_bf16(aq[kk], kf[kk], accS, 0, 0, 0);
#pragma unroll
    for (int r = 0; r < 16; ++r) rsum[r] += exp2f(accS[r]);

    if ((jt == it) && (wi == wj)) {               // wave-uniform branch
#pragma unroll
      for (int r = 0; r < 16; ++r) {
        const int lrr = (r & 3) + 8 * (r >> 2);
        if ((lrr + 4 * lh) == l31) sdiag[32 * wi + l31] = accS[r];
      }
    }
  }

  // reduce row partials across the 32 lanes sharing each row
#pragma unroll
  for (int r = 0; r < 16; ++r) {
    float v = rsum[r];
    v += __shfl_xor(v, 1);
    v += __shfl_xor(v, 2);
    v += __shfl_xor(v, 4);
    v += __shfl_xor(v, 8);
    v += __shfl_xor(v, 16);
    rsum[r] = v;
  }
  if (l31 == 0) {
#pragma unroll
    for (int r = 0; r < 16; ++r) {
      int lr = (r & 3) + 8 * (r >> 2) + 4 * lh;
      rssum[(32 * wi + lr) * 2 + wj] = rsum[r];
    }
  }
  __syncthreads();
  if (tid < 64) {
    float S = rssum[2 * tid] + rssum[2 * tid + 1];
    attw[tid] = exp2f(sdiag[tid]) / S;
  }
  __syncthreads();
  // out_pre[b*2048 + i][h*64 + d] = diag * v   (bf16)
  {
    int r = tid >> 2, dd = (tid & 3) * 16;
    float a = attw[r];
    int b = bh >> 3, h = bh & 7;
    const u16* vp = vb + (long)(i0 + r) * 64 + dd;
    u16* op = outp + ((long)(b * 2048 + i0 + r)) * 512 + h * 64 + dd;
    uint4 v0 = *(const uint4*)vp;
    uint4 v1 = *(const uint4*)(vp + 8);
    uint32_t vin[8] = {v0.x, v0.y, v0.z, v0.w, v1.x, v1.y, v1.z, v1.w};
    uint32_t vout[8];
#pragma unroll
    for (int e = 0; e < 8; ++e) {
      float lo = bf2f((u16)(vin[e] & 0xffffu)) * a;
      float hi = bf2f((u16)(vin[e] >> 16)) * a;
      vout[e] = pkbf(lo, hi);
    }
    uint4 o0 = {vout[0], vout[1], vout[2], vout[3]};
    uint4 o1 = {vout[4], vout[5], vout[6], vout[7]};
    *(uint4*)op = o0;
    *(uint4*)(op + 8) = o1;
  }
}

// ---------------------------------------------------------------------------
extern "C" void kernel_launch(void* const* d_in, const int* in_sizes, int n_in,
                              void* d_out, int out_size, void* d_ws, size_t ws_size,
                              hipStream_t stream) {
  (void)in_sizes; (void)n_in; (void)out_size; (void)ws_size;
  const float* q_in = (const float*)d_in[0];
  const float* k_in = (const float*)d_in[1];
  const float* v_in = (const float*)d_in[2];
  const float* Wq_w = (const float*)d_in[3];
  const float* Wq_b = (const float*)d_in[4];
  const float* Wk_w = (const float*)d_in[5];
  const float* Wk_b = (const float*)d_in[6];
  const float* Wv_w = (const float*)d_in[7];
  const float* Wv_b = (const float*)d_in[8];
  const float* Wo_w = (const float*)d_in[9];
  const float* Wo_b = (const float*)d_in[10];
  const float* Wp_w = (const float*)d_in[11];
  const float* Wp_b = (const float*)d_in[12];

  char* ws = (char*)d_ws;
  u16* xq   = (u16*)(ws + 0);         // 8 MB  bf16 q_in
  u16* xk   = (u16*)(ws + 8388608);   // 8 MB
  u16* xv   = (u16*)(ws + 16777216);  // 8 MB
  u16* wq   = (u16*)(ws + 25165824);  // 512 KB each
  u16* wk   = (u16*)(ws + 25690112);
  u16* wv   = (u16*)(ws + 26214400);
  u16* wo   = (u16*)(ws + 26738688);
  u16* wp   = (u16*)(ws + 27262976);  // 4096x64 bf16 (row 4095 zero)
  u16* q_ws = (u16*)(ws + 27787264);  // (b,h,l,d) bf16, pre-scaled log2e/8
  u16* k_ws = (u16*)(ws + 36175872);
  u16* v_ws = (u16*)(ws + 44564480);
  u16* opre = (u16*)(ws + 52953088);  // (b*l, h*d) bf16 diag-scaled v

  prep_kernel<<<6784, 256, 0, stream>>>(q_in, k_in, v_in, Wq_w, Wk_w, Wv_w, Wo_w, Wp_w,
                                        xq, xk, xv, wq, wk, wv, wo, wp);
  qkv_gemm<<<768, 256, 0, stream>>>(xq, xk, xv, wq, wk, wv, Wq_b, Wk_b, Wv_b,
                                    q_ws, k_ws, v_ws);
  attn_kernel<<<1024, 256, 0, stream>>>(q_ws, k_ws, v_ws, wp, Wp_b, opre);
  gemm_bt<<<256, 256, 0, stream>>>(opre, wo, Wo_b, (float*)d_out);
}